// Round 11
// baseline (407.469 us; speedup 1.0000x reference)
//
#include <hip/hip_runtime.h>

typedef __attribute__((ext_vector_type(8))) short s16x8;
typedef __attribute__((ext_vector_type(4))) float f32x4;

#define BB   512
#define LL   2048
#define DD   128
#define HH   128
#define SUB  128              // leaves per subtree
#define NSUB (LL / SUB)       // 16 subtrees per sample
#define NBLK (BB * NSUB)      // 8192 subtrees
#define K1ROWS 8              // rows k1 leaves per subtree (lev0'..lev3)
#define K2ROWS (NSUB * K1ROWS)  // 128 rows per sample into k2 (16 MB ws)

// f32 -> bf16 bits, RNE
__device__ __forceinline__ short f2bf(float x) {
  unsigned u = __builtin_bit_cast(unsigned, x);
  u += 0x7fffu + ((u >> 16) & 1u);
  return (short)(u >> 16);
}
// packed f32x2 -> bf16x2 (gfx950 v_cvt_pk_bf16_f32, RNE)
__device__ __forceinline__ unsigned pk_bf16(float a, float b) {
  unsigned r;
  asm("v_cvt_pk_bf16_f32 %0, %1, %2" : "=v"(r) : "v"(a), "v"(b));
  return r;
}
// tanh via exp; valid-row preacts norm-bounded; garbage rows write-masked
__device__ __forceinline__ float tanh_fast(float x) {
  float e2 = __expf(2.f * x);
  return (e2 - 1.f) * __builtin_amdgcn_rcpf(e2 + 1.f);
}

// LDS byte address for [row][inner(bytes)] in a [*][256B] bf16 tile; XOR
// swizzle breaks the 256B-row-stride bank alignment for strided ds_read_b128.
__device__ __forceinline__ int swz(int row, int inner) {
  return row * 256 + (inner ^ (((row >> 1) & 7) << 4));
}

// ---- prep (one launch, 161 blocks):
//  b<128   : WmT[n][k] = (k<128 ? (Win@Wc_top)[k][n] : (Win@Wc_bot)[k-128][n])
//  b in [128,160): WcT[n][k] = Wcomp[k][n] bf16
//  b==160  : b1[n] = bin@(Wc_top+Wc_bot)[:,n] + bcomp[n]  (fp32)
__global__ __launch_bounds__(256) void k_prep(
    const float* __restrict__ Win, const float* __restrict__ Wcomp,
    const float* __restrict__ bin, const float* __restrict__ bcomp,
    short* __restrict__ WmT, short* __restrict__ WcT,
    float* __restrict__ b1f) {
  const int b = blockIdx.x, t = threadIdx.x;
  if (b < 128) {
    const int d = b;            // k-index of the folded E-dot
    const int half = t >> 7, n = t & 127;
    float acc = 0.f;
    for (int k = 0; k < 128; ++k)
      acc += Win[d * 128 + k] * Wcomp[(k + 128 * half) * 128 + n];
    WmT[n * 256 + half * 128 + d] = f2bf(acc);
  } else if (b < 160) {
    for (int idx = (b - 128) * 256 + t; idx < 128 * 256; idx += 32 * 256) {
      int n = idx >> 8, k = idx & 255;
      WcT[idx] = f2bf(Wcomp[k * 128 + n]);
    }
  } else {
    if (t < 128) {
      float acc = bcomp[t];
      for (int k = 0; k < 128; ++k)
        acc += bin[k] * (Wcomp[k * 128 + t] + Wcomp[(k + 128) * 128 + t]);
      b1f[t] = acc;
    }
  }
}

// One 16-row tree M-tile: A row i = concat(src[2*(mt_in*16+i)], src[...+1]),
// K=256 against the given B-fragments. setprio(1) around the MFMA cluster
// (T5): resident blocks sit at diverse phases, scheduler favors MFMA waves.
__device__ __forceinline__ void tree_mm(const short* src, int mt_in,
                                        const s16x8 (&wf)[8][2], int lm,
                                        int lh, f32x4& c0, f32x4& c1) {
  s16x8 a[8];
#pragma unroll
  for (int kt = 0; kt < 8; ++kt) {
    int k = kt * 32 + lh * 8;
    int rowbuf = 2 * (mt_in * 16 + lm) + (k >> 7);
    a[kt] = *(const s16x8*)((const char*)src + swz(rowbuf, (k & 127) * 2));
  }
  c0 = (f32x4){0.f, 0.f, 0.f, 0.f};
  c1 = (f32x4){0.f, 0.f, 0.f, 0.f};
  __builtin_amdgcn_s_setprio(1);
#pragma unroll
  for (int kt = 0; kt < 8; ++kt) {
    c0 = __builtin_amdgcn_mfma_f32_16x16x32_bf16(a[kt], wf[kt][0], c0, 0, 0, 0);
    c1 = __builtin_amdgcn_mfma_f32_16x16x32_bf16(a[kt], wf[kt][1], c1, 0, 0, 0);
  }
  __builtin_amdgcn_s_setprio(0);
}

// k1: chunked gather+lev0' pipeline through two 8 KB chunk buffers (folded
// lev0' tile mt reads only E rows 32mt..32mt+31, so the full E matrix is
// never LDS-resident). 8+8+16 = 32 KB -> 4 blocks/CU at launch_bounds(256,4).
__global__ __launch_bounds__(256, 4) void k_subtree(
    const int* __restrict__ ids, const float* __restrict__ emb,
    const short* __restrict__ WmT, const short* __restrict__ WcT,
    const float* __restrict__ b1f, const float* __restrict__ bcomp,
    short* __restrict__ wsbf) {
  __shared__ __align__(16) short ldsC[2][32 * 128];  // 2 x 8 KB chunk buffers
  __shared__ __align__(16) short ldsE[64 * 128];     // 16 KB lev0' output
  const int blk = blockIdx.x, tid = threadIdx.x;
  const int wave = tid >> 6, lane = tid & 63;
  const int lh = lane >> 4, lm = lane & 15;
  const int n0 = wave * 32;
  const int col0 = n0 + 2 * lm;  // lane owns cols col0, col0+1
  const int gr = tid >> 5;       // gather row-within-8 (0..7)
  const int gc = tid & 31;       // gather col (float4 index)

  // leaf ids
  int idv[16];
#pragma unroll
  for (int it = 0; it < 16; ++it)
    idv[it] = ids[(long)blk * SUB + it * 8 + gr];

  const float2 b1v = *(const float2*)(b1f + col0);
  const float2 bcv = *(const float2*)(bcomp + col0);

  // gather chunk 0 (E rows 0-31 -> local rows 0-31 of ldsC[0])
#pragma unroll
  for (int it = 0; it < 4; ++it) {
    const float4 v = ((const float4*)(emb + (long)idv[it] * DD))[gc];
    uint2 pv;
    pv.x = pk_bf16(v.x, v.y);
    pv.y = pk_bf16(v.z, v.w);
    *(uint2*)((char*)ldsC[0] + swz(it * 8 + gr, gc * 8)) = pv;
  }

  // weight fragments for lev0' (folded M)
  s16x8 wf[8][2];
#pragma unroll
  for (int kt = 0; kt < 8; ++kt)
#pragma unroll
    for (int nt = 0; nt < 2; ++nt)
      wf[kt][nt] = *(const s16x8*)(WmT + (col0 + nt) * 256 + kt * 32 + lh * 8);
  __syncthreads();

  // lev0' pipelined over chunks: issue chunk mt+1 loads, compute tile mt from
  // ldsC[mt&1] (local rows 0-31), write outputs to ldsE, land chunk mt+1 into
  // the other buffer, barrier. One barrier per tile.
#pragma unroll
  for (int mt = 0; mt < 4; ++mt) {
    const int cur = mt & 1;
    float4 g[4];
    if (mt < 3) {
#pragma unroll
      for (int j = 0; j < 4; ++j)
        g[j] = ((const float4*)(emb + (long)idv[(mt + 1) * 4 + j] * DD))[gc];
    }
    f32x4 c0, c1;
    tree_mm(ldsC[cur], 0, wf, lm, lh, c0, c1);
#pragma unroll
    for (int r = 0; r < 4; ++r) {
      int row = mt * 16 + lh * 4 + r;
      *(unsigned*)((char*)ldsE + swz(row, col0 * 2)) =
          pk_bf16(tanh_fast(c0[r] + b1v.x), tanh_fast(c1[r] + b1v.y));
    }
    if (mt < 3) {
#pragma unroll
      for (int j = 0; j < 4; ++j) {
        uint2 pv;
        pv.x = pk_bf16(g[j].x, g[j].y);
        pv.y = pk_bf16(g[j].z, g[j].w);
        *(uint2*)((char*)ldsC[cur ^ 1] + swz(j * 8 + gr, gc * 8)) = pv;
      }
    } else {
      // reload fragments from WcT (after last WmT MFMA; latency hides
      // under the barrier + lev1's first ds_reads)
#pragma unroll
      for (int kt = 0; kt < 8; ++kt)
#pragma unroll
        for (int nt = 0; nt < 2; ++nt)
          wf[kt][nt] =
              *(const s16x8*)(WcT + (col0 + nt) * 256 + kt * 32 + lh * 8);
    }
    __syncthreads();
  }

  // lev1: ldsE(64 rows) -> ldsC[0] rows 0-31 (chunk A last read at mt=2,
  // barriers since)
#pragma unroll 1
  for (int mt = 0; mt < 2; ++mt) {
    f32x4 c0, c1;
    tree_mm(ldsE, mt, wf, lm, lh, c0, c1);
#pragma unroll
    for (int r = 0; r < 4; ++r) {
      int row = mt * 16 + lh * 4 + r;
      *(unsigned*)((char*)ldsC[0] + swz(row, col0 * 2)) =
          pk_bf16(tanh_fast(c0[r] + bcv.x), tanh_fast(c1[r] + bcv.y));
    }
  }
  __syncthreads();

  // lev2: ldsC[0] (32 valid rows) -> ldsC[1] rows 0-15
  {
    f32x4 c0, c1;
    tree_mm(ldsC[0], 0, wf, lm, lh, c0, c1);
#pragma unroll
    for (int r = 0; r < 4; ++r) {
      int row = lh * 4 + r;
      *(unsigned*)((char*)ldsC[1] + swz(row, col0 * 2)) =
          pk_bf16(tanh_fast(c0[r] + bcv.x), tanh_fast(c1[r] + bcv.y));
    }
  }
  __syncthreads();

  // lev3: ldsC[1] rows 0-15 valid (rows 16-31 stale chunk-3 E data, finite)
  // -> global, 8 rows. D rows 0-7 use A pair-rows 0-15 only; masked beyond.
  {
    f32x4 c0, c1;
    tree_mm(ldsC[1], 0, wf, lm, lh, c0, c1);
#pragma unroll
    for (int r = 0; r < 4; ++r) {
      int row = lh * 4 + r;
      if (row < K1ROWS)
        *(unsigned*)(wsbf + ((long)blk * K1ROWS + row) * HH + col0) =
            pk_bf16(tanh_fast(c0[r] + bcv.x), tanh_fast(c1[r] + bcv.y));
    }
  }
}

// ---- k2: per-sample 128 rows -> root -> classifier (MFMA) ----
__global__ __launch_bounds__(256, 2) void k_tree2(
    const short* __restrict__ wsbf, const short* __restrict__ WcT,
    const float* __restrict__ bcomp, const float* __restrict__ Wcls,
    const float* __restrict__ bcls, float* __restrict__ out) {
  __shared__ __align__(16) short srcL[128 * 128];  // 32 KB
  __shared__ __align__(16) short dstS[64 * 128];   // 16 KB
  __shared__ float rootL[128];
  const int b = blockIdx.x, tid = threadIdx.x;
  const int wave = tid >> 6, lane = tid & 63;
  const int lh = lane >> 4, lm = lane & 15;
  const int n0 = wave * 32;
  const int col0 = n0 + 2 * lm;

  s16x8 wfc[8][2];
#pragma unroll
  for (int kt = 0; kt < 8; ++kt)
#pragma unroll
    for (int nt = 0; nt < 2; ++nt)
      wfc[kt][nt] = *(const s16x8*)(WcT + (col0 + nt) * 256 + kt * 32 + lh * 8);
  const float2 bcv = *(const float2*)(bcomp + col0);

  // load 128 rows of bf16 (16 B per lane, coalesced) -> srcL swizzled
#pragma unroll
  for (int it = 0; it < 8; ++it) {
    int row = it * 16 + (tid >> 4);
    s16x8 v = *(const s16x8*)(wsbf + ((long)b * K2ROWS + row) * HH + (tid & 15) * 8);
    *(s16x8*)((char*)srcL + swz(row, (tid & 15) * 16)) = v;
  }
  __syncthreads();

  const short* src = srcL;
  short* dst = dstS;
  // levels: 128->64->32->16->8->4->2->1 ; mtiles 4,2,1,1,1,1,1
  const int mtiles[7] = {4, 2, 1, 1, 1, 1, 1};
  const int rlim[7] = {64, 32, 16, 8, 4, 2, 1};
#pragma unroll 1
  for (int lev = 0; lev < 7; ++lev) {
    int nmt = mtiles[lev], rl = rlim[lev];
#pragma unroll 1
    for (int mt = 0; mt < nmt; ++mt) {
      f32x4 c0, c1;
      tree_mm(src, mt, wfc, lm, lh, c0, c1);
      if (lev == 6) {
        if (lh == 0) {
          rootL[col0] = tanh_fast(c0[0] + bcv.x);
          rootL[col0 + 1] = tanh_fast(c1[0] + bcv.y);
        }
      } else {
#pragma unroll
        for (int r = 0; r < 4; ++r) {
          int row = mt * 16 + lh * 4 + r;
          if (row < rl)
            *(unsigned*)((char*)dst + swz(row, col0 * 2)) =
                pk_bf16(tanh_fast(c0[r] + bcv.x), tanh_fast(c1[r] + bcv.y));
        }
      }
    }
    __syncthreads();
    const short* t = src;
    src = dst;
    dst = (short*)t;
  }

  // classifier: wave 0; lane -> (class = lane&1, k-chunk = lane>>1)
  if (wave == 0) {
    int c = lane & 1, kb = lane >> 1;
    float p = 0.f;
#pragma unroll
    for (int j = 0; j < 4; ++j) {
      int k = kb + 32 * j;
      p += rootL[k] * Wcls[k * 2 + c];
    }
#pragma unroll
    for (int m = 2; m <= 32; m <<= 1) p += __shfl_xor(p, m, 64);
    if (lane < 2) out[b * 2 + lane] = p + bcls[lane];
  }
}

extern "C" void kernel_launch(void* const* d_in, const int* in_sizes, int n_in,
                              void* d_out, int out_size, void* d_ws, size_t ws_size,
                              hipStream_t stream) {
  const int*   ids   = (const int*)d_in[0];
  const float* emb   = (const float*)d_in[1];
  const float* Win   = (const float*)d_in[2];
  const float* bin   = (const float*)d_in[3];
  const float* Wcomp = (const float*)d_in[4];
  const float* bcomp = (const float*)d_in[5];
  const float* Wcls  = (const float*)d_in[6];
  const float* bcls  = (const float*)d_in[7];
  char* wsb = (char*)d_ws;
  // layout: [wsbf 16 MB][WcT 64 KB][WmT 128 KB][b1 512 B]
  short* wsbf = (short*)wsb;
  const size_t WSBF_BYTES = (size_t)BB * NSUB * K1ROWS * HH * 2;  // 16 MB
  short* WcT = (short*)(wsb + WSBF_BYTES);
  short* WmT = (short*)(wsb + WSBF_BYTES + (64 << 10));
  float* b1f = (float*)(wsb + WSBF_BYTES + (192 << 10));
  float* out = (float*)d_out;

  hipLaunchKernelGGL(k_prep, dim3(161), dim3(256), 0, stream,
                     Win, Wcomp, bin, bcomp, WmT, WcT, b1f);
  hipLaunchKernelGGL(k_subtree, dim3(NBLK), dim3(256), 0, stream,
                     ids, emb, WmT, WcT, b1f, bcomp, wsbf);
  hipLaunchKernelGGL(k_tree2, dim3(BB), dim3(256), 0, stream,
                     wsbf, WcT, bcomp, Wcls, bcls, out);
}

// Round 12
// 175.697 us; speedup vs baseline: 2.3192x; 2.3192x over previous
//
#include <hip/hip_runtime.h>

typedef __attribute__((ext_vector_type(8))) short s16x8;
typedef __attribute__((ext_vector_type(4))) float f32x4;

#define BB   512
#define LL   2048
#define DD   128
#define HH   128
#define SUB  128              // leaves per subtree
#define NSUB (LL / SUB)       // 16 subtrees per sample
#define NBLK (BB * NSUB)      // 8192 subtrees
#define K1ROWS 8              // rows k1 leaves per subtree (lev0'..lev3)
#define K2ROWS (NSUB * K1ROWS)  // 128 rows per sample into k2 (16 MB ws)

// f32 -> bf16 bits, RNE
__device__ __forceinline__ short f2bf(float x) {
  unsigned u = __builtin_bit_cast(unsigned, x);
  u += 0x7fffu + ((u >> 16) & 1u);
  return (short)(u >> 16);
}
// packed f32x2 -> bf16x2 (gfx950 v_cvt_pk_bf16_f32, RNE)
__device__ __forceinline__ unsigned pk_bf16(float a, float b) {
  unsigned r;
  asm("v_cvt_pk_bf16_f32 %0, %1, %2" : "=v"(r) : "v"(a), "v"(b));
  return r;
}
// tanh via exp; valid-row preacts norm-bounded; garbage rows write-masked
__device__ __forceinline__ float tanh_fast(float x) {
  float e2 = __expf(2.f * x);
  return (e2 - 1.f) * __builtin_amdgcn_rcpf(e2 + 1.f);
}

// LDS byte address for [row][inner(bytes)] in a [*][256B] bf16 tile; XOR
// swizzle breaks the 256B-row-stride bank alignment for strided ds_read_b128.
__device__ __forceinline__ int swz(int row, int inner) {
  return row * 256 + (inner ^ (((row >> 1) & 7) << 4));
}

// ---- prep (one launch, 161 blocks):
//  b<128   : WmT[n][k] = (k<128 ? (Win@Wc_top)[k][n] : (Win@Wc_bot)[k-128][n])
//  b in [128,160): WcT[n][k] = Wcomp[k][n] bf16
//  b==160  : b1[n] = bin@(Wc_top+Wc_bot)[:,n] + bcomp[n]  (fp32)
__global__ __launch_bounds__(256) void k_prep(
    const float* __restrict__ Win, const float* __restrict__ Wcomp,
    const float* __restrict__ bin, const float* __restrict__ bcomp,
    short* __restrict__ WmT, short* __restrict__ WcT,
    float* __restrict__ b1f) {
  const int b = blockIdx.x, t = threadIdx.x;
  if (b < 128) {
    const int d = b;            // k-index of the folded E-dot
    const int half = t >> 7, n = t & 127;
    float acc = 0.f;
    for (int k = 0; k < 128; ++k)
      acc += Win[d * 128 + k] * Wcomp[(k + 128 * half) * 128 + n];
    WmT[n * 256 + half * 128 + d] = f2bf(acc);
  } else if (b < 160) {
    for (int idx = (b - 128) * 256 + t; idx < 128 * 256; idx += 32 * 256) {
      int n = idx >> 8, k = idx & 255;
      WcT[idx] = f2bf(Wcomp[k * 128 + n]);
    }
  } else {
    if (t < 128) {
      float acc = bcomp[t];
      for (int k = 0; k < 128; ++k)
        acc += bin[k] * (Wcomp[k * 128 + t] + Wcomp[(k + 128) * 128 + t]);
      b1f[t] = acc;
    }
  }
}

// Single-column tree M-tile: A row i = concat(src[2*(mt*16+i)], src[...+1]),
// K=256 against ONE B-fragment column. 8 MFMA per wave per tile.
__device__ __forceinline__ f32x4 tree_mm1(const short* src, int mt_in,
                                          const s16x8 (&wf)[8], int lm,
                                          int lh) {
  s16x8 a[8];
#pragma unroll
  for (int kt = 0; kt < 8; ++kt) {
    int k = kt * 32 + lh * 8;
    int rowbuf = 2 * (mt_in * 16 + lm) + (k >> 7);
    a[kt] = *(const s16x8*)((const char*)src + swz(rowbuf, (k & 127) * 2));
  }
  f32x4 c = {0.f, 0.f, 0.f, 0.f};
#pragma unroll
  for (int kt = 0; kt < 8; ++kt)
    c = __builtin_amdgcn_mfma_f32_16x16x32_bf16(a[kt], wf[kt], c, 0, 0, 0);
  return c;
}

// k1: 512 threads, 8 waves, ONE column per lane (wave w owns cols
// w*16..w*16+15). wf[8] = 32 VGPR (half of the 2-col shape) -> fits the
// 85-VGPR cap of (512,6): 3 blocks/CU = 24 waves/CU, per-wave chains halved.
// Structure/phases/math identical to R8.
__global__ __launch_bounds__(512, 6) void k_subtree(
    const int* __restrict__ ids, const float* __restrict__ emb,
    const short* __restrict__ WmT, const short* __restrict__ WcT,
    const float* __restrict__ b1f, const float* __restrict__ bcomp,
    short* __restrict__ wsbf) {
  __shared__ __align__(16) short ldsB[128 * 128];  // 32 KB: E pairs / pong
  __shared__ __align__(16) short ldsE[64 * 128];   // 16 KB: ping
  const int blk = blockIdx.x, tid = threadIdx.x;
  const int wave = tid >> 6, lane = tid & 63;
  const int lh = lane >> 4, lm = lane & 15;
  const int col0 = wave * 16 + lm;  // lane owns ONE col
  const int gr = tid >> 5;          // gather row-within-16 (0..15)
  const int gc = tid & 31;          // gather col (float4 index)

  // leaf ids (8 iters x 16 rows = 128 rows)
  int idv[8];
#pragma unroll
  for (int it = 0; it < 8; ++it)
    idv[it] = ids[(long)blk * SUB + it * 16 + gr];

  const float b1s = b1f[col0];
  const float bcs = bcomp[col0];

  // gather all 128 E rows -> ldsB (bf16, swizzled), single phase
#pragma unroll
  for (int it = 0; it < 8; ++it) {
    int r = it * 16 + gr;
    const float4 v = ((const float4*)(emb + (long)idv[it] * DD))[gc];
    uint2 pv;
    pv.x = pk_bf16(v.x, v.y);
    pv.y = pk_bf16(v.z, v.w);
    *(uint2*)((char*)ldsB + swz(r, gc * 8)) = pv;
  }

  // weight fragments for lev0' (folded M); idv now dead
  s16x8 wf[8];
#pragma unroll
  for (int kt = 0; kt < 8; ++kt)
    wf[kt] = *(const s16x8*)(WmT + col0 * 256 + kt * 32 + lh * 8);
  __syncthreads();

  // lev0': E pairs (rows 0-127) x M -> ldsE rows 0-63 (tanh, folded bias)
#pragma unroll 1
  for (int mt = 0; mt < 4; ++mt) {
    f32x4 c = tree_mm1(ldsB, mt, wf, lm, lh);
#pragma unroll
    for (int r = 0; r < 4; ++r) {
      int row = mt * 16 + lh * 4 + r;
      *(short*)((char*)ldsE + swz(row, col0 * 2)) = f2bf(tanh_fast(c[r] + b1s));
    }
  }
  // reload fragments from WcT (after last WmT MFMA; latency over barrier)
#pragma unroll
  for (int kt = 0; kt < 8; ++kt)
    wf[kt] = *(const s16x8*)(WcT + col0 * 256 + kt * 32 + lh * 8);
  __syncthreads();

  // lev1: ldsE(64) -> ldsB rows 0-31
#pragma unroll 1
  for (int mt = 0; mt < 2; ++mt) {
    f32x4 c = tree_mm1(ldsE, mt, wf, lm, lh);
#pragma unroll
    for (int r = 0; r < 4; ++r) {
      int row = mt * 16 + lh * 4 + r;
      *(short*)((char*)ldsB + swz(row, col0 * 2)) = f2bf(tanh_fast(c[r] + bcs));
    }
  }
  __syncthreads();

  // lev2: ldsB(32) -> ldsE rows 0-15 (all valid)
  {
    f32x4 c = tree_mm1(ldsB, 0, wf, lm, lh);
#pragma unroll
    for (int r = 0; r < 4; ++r) {
      int row = lh * 4 + r;
      *(short*)((char*)ldsE + swz(row, col0 * 2)) = f2bf(tanh_fast(c[r] + bcs));
    }
  }
  __syncthreads();

  // lev3: ldsE rows 0-15 valid (16-31 stale lev0' output, finite, in (-1,1))
  // -> global, 8 rows. D rows 0-7 use A pair-rows 0-15 only; masked beyond.
  {
    f32x4 c = tree_mm1(ldsE, 0, wf, lm, lh);
#pragma unroll
    for (int r = 0; r < 4; ++r) {
      int row = lh * 4 + r;
      if (row < K1ROWS)
        wsbf[((long)blk * K1ROWS + row) * HH + col0] =
            f2bf(tanh_fast(c[r] + bcs));
    }
  }
}

// ---- k2: per-sample 128 rows -> root -> classifier (MFMA) ----
__global__ __launch_bounds__(256, 2) void k_tree2(
    const short* __restrict__ wsbf, const short* __restrict__ WcT,
    const float* __restrict__ bcomp, const float* __restrict__ Wcls,
    const float* __restrict__ bcls, float* __restrict__ out) {
  __shared__ __align__(16) short srcL[128 * 128];  // 32 KB
  __shared__ __align__(16) short dstS[64 * 128];   // 16 KB
  __shared__ float rootL[128];
  const int b = blockIdx.x, tid = threadIdx.x;
  const int wave = tid >> 6, lane = tid & 63;
  const int lh = lane >> 4, lm = lane & 15;
  const int n0 = wave * 32;
  const int col0 = n0 + 2 * lm;

  s16x8 wfc[8][2];
#pragma unroll
  for (int kt = 0; kt < 8; ++kt)
#pragma unroll
    for (int nt = 0; nt < 2; ++nt)
      wfc[kt][nt] = *(const s16x8*)(WcT + (col0 + nt) * 256 + kt * 32 + lh * 8);
  const float2 bcv = *(const float2*)(bcomp + col0);

  // load 128 rows of bf16 (16 B per lane, coalesced) -> srcL swizzled
#pragma unroll
  for (int it = 0; it < 8; ++it) {
    int row = it * 16 + (tid >> 4);
    s16x8 v = *(const s16x8*)(wsbf + ((long)b * K2ROWS + row) * HH + (tid & 15) * 8);
    *(s16x8*)((char*)srcL + swz(row, (tid & 15) * 16)) = v;
  }
  __syncthreads();

  const short* src = srcL;
  short* dst = dstS;
  // levels: 128->64->32->16->8->4->2->1 ; mtiles 4,2,1,1,1,1,1
  const int mtiles[7] = {4, 2, 1, 1, 1, 1, 1};
  const int rlim[7] = {64, 32, 16, 8, 4, 2, 1};
#pragma unroll 1
  for (int lev = 0; lev < 7; ++lev) {
    int nmt = mtiles[lev], rl = rlim[lev];
#pragma unroll 1
    for (int mt = 0; mt < nmt; ++mt) {
      s16x8 a[8];
#pragma unroll
      for (int kt = 0; kt < 8; ++kt) {
        int k = kt * 32 + lh * 8;
        int rowbuf = 2 * (mt * 16 + lm) + (k >> 7);
        a[kt] = *(const s16x8*)((const char*)src + swz(rowbuf, (k & 127) * 2));
      }
      f32x4 c0 = {0.f, 0.f, 0.f, 0.f}, c1 = {0.f, 0.f, 0.f, 0.f};
#pragma unroll
      for (int kt = 0; kt < 8; ++kt) {
        c0 = __builtin_amdgcn_mfma_f32_16x16x32_bf16(a[kt], wfc[kt][0], c0, 0, 0, 0);
        c1 = __builtin_amdgcn_mfma_f32_16x16x32_bf16(a[kt], wfc[kt][1], c1, 0, 0, 0);
      }
      if (lev == 6) {
        if (lh == 0) {
          rootL[col0] = tanh_fast(c0[0] + bcv.x);
          rootL[col0 + 1] = tanh_fast(c1[0] + bcv.y);
        }
      } else {
#pragma unroll
        for (int r = 0; r < 4; ++r) {
          int row = mt * 16 + lh * 4 + r;
          if (row < rl)
            *(unsigned*)((char*)dst + swz(row, col0 * 2)) =
                pk_bf16(tanh_fast(c0[r] + bcv.x), tanh_fast(c1[r] + bcv.y));
        }
      }
    }
    __syncthreads();
    const short* t = src;
    src = dst;
    dst = (short*)t;
  }

  // classifier: wave 0; lane -> (class = lane&1, k-chunk = lane>>1)
  if (wave == 0) {
    int c = lane & 1, kb = lane >> 1;
    float p = 0.f;
#pragma unroll
    for (int j = 0; j < 4; ++j) {
      int k = kb + 32 * j;
      p += rootL[k] * Wcls[k * 2 + c];
    }
#pragma unroll
    for (int m = 2; m <= 32; m <<= 1) p += __shfl_xor(p, m, 64);
    if (lane < 2) out[b * 2 + lane] = p + bcls[lane];
  }
}

extern "C" void kernel_launch(void* const* d_in, const int* in_sizes, int n_in,
                              void* d_out, int out_size, void* d_ws, size_t ws_size,
                              hipStream_t stream) {
  const int*   ids   = (const int*)d_in[0];
  const float* emb   = (const float*)d_in[1];
  const float* Win   = (const float*)d_in[2];
  const float* bin   = (const float*)d_in[3];
  const float* Wcomp = (const float*)d_in[4];
  const float* bcomp = (const float*)d_in[5];
  const float* Wcls  = (const float*)d_in[6];
  const float* bcls  = (const float*)d_in[7];
  char* wsb = (char*)d_ws;
  // layout: [wsbf 16 MB][WcT 64 KB][WmT 128 KB][b1 512 B]
  short* wsbf = (short*)wsb;
  const size_t WSBF_BYTES = (size_t)BB * NSUB * K1ROWS * HH * 2;  // 16 MB
  short* WcT = (short*)(wsb + WSBF_BYTES);
  short* WmT = (short*)(wsb + WSBF_BYTES + (64 << 10));
  float* b1f = (float*)(wsb + WSBF_BYTES + (192 << 10));
  float* out = (float*)d_out;

  hipLaunchKernelGGL(k_prep, dim3(161), dim3(256), 0, stream,
                     Win, Wcomp, bin, bcomp, WmT, WcT, b1f);
  hipLaunchKernelGGL(k_subtree, dim3(NBLK), dim3(512), 0, stream,
                     ids, emb, WmT, WcT, b1f, bcomp, wsbf);
  hipLaunchKernelGGL(k_tree2, dim3(BB), dim3(256), 0, stream,
                     wsbf, WcT, bcomp, Wcls, bcls, out);
}